// Round 17
// baseline (851.648 us; speedup 1.0000x reference)
//
#include <hip/hip_runtime.h>
#include <math.h>

#define NN 50000
#define NF 512
#define NH 512
#define NK 16

typedef __attribute__((ext_vector_type(8))) short bf16x8;
typedef __attribute__((ext_vector_type(4))) float f32x4;
typedef __attribute__((ext_vector_type(2))) float f32x2;

#define RPART 128   // reduce_cs_nl blocks
#define TPART 2048  // trace blocks

__device__ __forceinline__ unsigned short f2bf(float f) {
  unsigned u = __float_as_uint(f);
  unsigned r = (u + 0x7fffu + ((u >> 16) & 1u)) >> 16;
  return (unsigned short)r;
}

// ---------------- fp32 -> bf16 feature conversion (once) ----------------
__global__ __launch_bounds__(256) void conv_feat(const float* __restrict__ X,
                                                 unsigned short* __restrict__ Xb, int n4) {
  for (int i = blockIdx.x * blockDim.x + threadIdx.x; i < n4; i += gridDim.x * blockDim.x) {
    float4 v = *(const float4*)(X + (size_t)i * 4);
    ushort4 o;
    o.x = f2bf(v.x); o.y = f2bf(v.y); o.z = f2bf(v.z); o.w = f2bf(v.w);
    *(ushort4*)(Xb + (size_t)i * 4) = o;
  }
}

// ---------------- W -> packed bf16: Bp[((k>>3)*512 + col)*8 + (k&7)] ----------------
__global__ __launch_bounds__(256) void conv_w(const float* __restrict__ W,
                                              unsigned short* __restrict__ Bp) {
  int idx = blockIdx.x * blockDim.x + threadIdx.x;
  int k = idx >> 9, col = idx & 511;
  Bp[((size_t)(k >> 3) * 512 + col) * 8 + (k & 7)] = f2bf(W[idx]);
}

// ---------------- GEMM: xw_fp8[Mpad,512] = feat_bf @ W (bf16 MFMA, fp8 out, row-major) ----------------
#define GBM 128
#define GBN 128
#define GBK 32

__global__ __launch_bounds__(256) void gemm_bf16(const unsigned short* __restrict__ A,
                                                 const unsigned short* __restrict__ Bp,
                                                 unsigned char* __restrict__ C8, int M) {
  __shared__ bf16x8 Abuf[512];
  __shared__ bf16x8 Bbuf[512];
  const int tid = threadIdx.x;
  const int lane = tid & 63;
  const int w = tid >> 6;
  const int wr = w >> 1, wc = w & 1;
  const int bm0 = blockIdx.y * GBM;
  const int bn0 = blockIdx.x * GBN;

  f32x4 acc[4][4];
#pragma unroll
  for (int m = 0; m < 4; ++m)
#pragma unroll
    for (int n = 0; n < 4; ++n)
      acc[m][n] = (f32x4){0.f, 0.f, 0.f, 0.f};

  for (int k0 = 0; k0 < NF; k0 += GBK) {
#pragma unroll
    for (int c = 0; c < 2; ++c) {
      int slot = c * 256 + tid;
      int kc = slot >> 7;
      int rc = slot & 127;
      int gr = bm0 + rc; if (gr > M - 1) gr = M - 1;
      Abuf[slot] = *(const bf16x8*)(A + (size_t)gr * NF + k0 + kc * 8);
      int kcg = (k0 >> 3) + kc;
      Bbuf[slot] = *(const bf16x8*)(Bp + ((size_t)kcg * NH + bn0 + rc) * 8);
    }
    __syncthreads();
    bf16x8 af[4], bfr[4];
#pragma unroll
    for (int m = 0; m < 4; ++m)
      af[m] = Abuf[(lane >> 4) * 128 + wr * 64 + m * 16 + (lane & 15)];
#pragma unroll
    for (int n = 0; n < 4; ++n)
      bfr[n] = Bbuf[(lane >> 4) * 128 + wc * 64 + n * 16 + (lane & 15)];
#pragma unroll
    for (int m = 0; m < 4; ++m)
#pragma unroll
      for (int n = 0; n < 4; ++n)
        acc[m][n] = __builtin_amdgcn_mfma_f32_16x16x32_bf16(af[m], bfr[n], acc[m][n], 0, 0, 0);
    __syncthreads();
  }
#pragma unroll
  for (int m = 0; m < 4; ++m) {
    int grow_base = bm0 + wr * 64 + m * 16 + (lane >> 4) * 4;
#pragma unroll
    for (int r = 0; r < 4; ++r) {
      int grow = grow_base + r;
#pragma unroll
      for (int n = 0; n < 4; ++n) {
        int gcol = bn0 + wc * 64 + n * 16 + (lane & 15);
        int pk = __builtin_amdgcn_cvt_pk_fp8_f32(acc[m][n][r], 0.f, 0, false);
        C8[(size_t)grow * NH + gcol] = (unsigned char)(pk & 0xFF);
      }
    }
  }
}

// ---------------- edge histogram + degrees ----------------
__global__ void hist_kernel(const int* __restrict__ src, const int* __restrict__ dst,
                            const float* __restrict__ gv, int* __restrict__ counts,
                            float* __restrict__ deg, int E) {
  int e = blockIdx.x * blockDim.x + threadIdx.x;
  if (e < E) {
    atomicAdd(&counts[src[e]], 1);
    atomicAdd(&deg[dst[e]], gv[e]);
  }
}

// ---------------- parallel 3-phase exclusive scan ----------------
__global__ __launch_bounds__(256) void scanA(const int* __restrict__ counts,
                                             int* __restrict__ bsum, int n) {
  __shared__ int ws[4];
  int i0 = blockIdx.x * 1024 + threadIdx.x * 4;
  int s = 0;
  if (i0 + 3 < n) {
    int4 v = *(const int4*)(counts + i0);
    s = v.x + v.y + v.z + v.w;
  } else {
#pragma unroll
    for (int j = 0; j < 4; ++j) if (i0 + j < n) s += counts[i0 + j];
  }
#pragma unroll
  for (int off = 32; off >= 1; off >>= 1) s += __shfl_down(s, off, 64);
  int wv = threadIdx.x >> 6, ln = threadIdx.x & 63;
  if (ln == 0) ws[wv] = s;
  __syncthreads();
  if (threadIdx.x == 0) bsum[blockIdx.x] = ws[0] + ws[1] + ws[2] + ws[3];
}

__global__ __launch_bounds__(64) void scanB(const int* __restrict__ bsum,
                                            int* __restrict__ bbase,
                                            int* __restrict__ offs, int nb, int n) {
  int ln = threadIdx.x;
  int v = ln < nb ? bsum[ln] : 0;
  int x = v;
#pragma unroll
  for (int d = 1; d < 64; d <<= 1) {
    int y = __shfl_up(x, d, 64);
    if (ln >= d) x += y;
  }
  if (ln < nb) bbase[ln] = x - v;
  if (ln == nb - 1) offs[n] = x;
}

__global__ __launch_bounds__(256) void scanC(const int* __restrict__ counts,
                                             const int* __restrict__ bbase,
                                             int* __restrict__ offs,
                                             int* __restrict__ cursor, int n) {
  __shared__ int ws[4];
  int i0 = blockIdx.x * 1024 + threadIdx.x * 4;
  int c0 = 0, c1 = 0, c2 = 0, c3 = 0;
  if (i0 + 3 < n) {
    int4 v = *(const int4*)(counts + i0);
    c0 = v.x; c1 = v.y; c2 = v.z; c3 = v.w;
  } else {
    if (i0 < n)     c0 = counts[i0];
    if (i0 + 1 < n) c1 = counts[i0 + 1];
    if (i0 + 2 < n) c2 = counts[i0 + 2];
    if (i0 + 3 < n) c3 = counts[i0 + 3];
  }
  int s = c0 + c1 + c2 + c3;
  int x = s;
  int wv = threadIdx.x >> 6, ln = threadIdx.x & 63;
#pragma unroll
  for (int d = 1; d < 64; d <<= 1) {
    int y = __shfl_up(x, d, 64);
    if (ln >= d) x += y;
  }
  if (ln == 63) ws[wv] = x;
  __syncthreads();
  int woff = 0;
  if (wv > 0) woff += ws[0];
  if (wv > 1) woff += ws[1];
  if (wv > 2) woff += ws[2];
  int exc = bbase[blockIdx.x] + woff + x - s;
  if (i0 < n)     { offs[i0]     = exc;                cursor[i0]     = exc; }
  if (i0 + 1 < n) { offs[i0 + 1] = exc + c0;           cursor[i0 + 1] = exc + c0; }
  if (i0 + 2 < n) { offs[i0 + 2] = exc + c0 + c1;      cursor[i0 + 2] = exc + c0 + c1; }
  if (i0 + 3 < n) { offs[i0 + 3] = exc + c0 + c1 + c2; cursor[i0 + 3] = exc + c0 + c1 + c2; }
}

// ---------------- scatter edges into CSR (paired 8B stores) ----------------
__global__ void scatter_kernel(const int* __restrict__ src, const int* __restrict__ dst,
                               const float* __restrict__ gn, int* __restrict__ cursor,
                               int2* __restrict__ epair, int E) {
  int e = blockIdx.x * blockDim.x + threadIdx.x;
  if (e < E) {
    int pos = atomicAdd(&cursor[src[e]], 1);
    int2 v; v.x = dst[e]; v.y = __float_as_int(gn[e]);
    epair[pos] = v;
  }
}

// ---------------- fused per-node: fp8 SpMM (dwordx2/lane, 4 waves x 4-deep) ----------------
__global__ __launch_bounds__(256) void node_kernel(const unsigned* __restrict__ xw8,
                                                   const int* __restrict__ offs,
                                                   const int2* __restrict__ epair,
                                                   const float* __restrict__ bias,
                                                   const float* __restrict__ Wt,
                                                   const float* __restrict__ bt,
                                                   float* __restrict__ assign, int n) {
  __shared__ int sk[256];
  __shared__ float sv[256];
  __shared__ float cmb[3][64][8];
  __shared__ float red[NK];
  int node = blockIdx.x;
  if (node >= n) return;
  const int t = threadIdx.x;
  const int r = t & 63;        // 8-dim group within row (dims 8r..8r+7)
  const int q = t >> 6;        // wave = edge subgroup 0..3
  const int beg = offs[node], end = offs[node + 1];
  const uint2* rowp = (const uint2*)xw8;   // row idx -> idx*64 + r

  float a[8] = {0.f, 0.f, 0.f, 0.f, 0.f, 0.f, 0.f, 0.f};

#define ACC2(V, G) {                                                  \
    f32x2 l0_ = __builtin_amdgcn_cvt_pk_f32_fp8((V).x, false);        \
    f32x2 h0_ = __builtin_amdgcn_cvt_pk_f32_fp8((V).x, true);         \
    f32x2 l1_ = __builtin_amdgcn_cvt_pk_f32_fp8((V).y, false);        \
    f32x2 h1_ = __builtin_amdgcn_cvt_pk_f32_fp8((V).y, true);         \
    a[0] = fmaf(G, l0_[0], a[0]); a[1] = fmaf(G, l0_[1], a[1]);       \
    a[2] = fmaf(G, h0_[0], a[2]); a[3] = fmaf(G, h0_[1], a[3]);       \
    a[4] = fmaf(G, l1_[0], a[4]); a[5] = fmaf(G, l1_[1], a[5]);       \
    a[6] = fmaf(G, h1_[0], a[6]); a[7] = fmaf(G, h1_[1], a[7]); }

  for (int cbeg = beg; cbeg < end; cbeg += 256) {
    int d = end - cbeg; if (d > 256) d = 256;
    if (t < d) { int2 p = epair[cbeg + t]; sk[t] = p.x; sv[t] = __int_as_float(p.y); }
    __syncthreads();
    int nf = d & ~15;
    for (int b = 0; b < nf; b += 16) {
      // 4 independent 8B row-loads in flight per lane
      int e0 = b + q, e1 = b + 4 + q, e2 = b + 8 + q, e3 = b + 12 + q;
      int i0 = sk[e0], i1 = sk[e1], i2 = sk[e2], i3 = sk[e3];
      uint2 v0 = rowp[(size_t)i0 * 64 + r];
      uint2 v1 = rowp[(size_t)i1 * 64 + r];
      uint2 v2 = rowp[(size_t)i2 * 64 + r];
      uint2 v3 = rowp[(size_t)i3 * 64 + r];
      float g0 = sv[e0], g1 = sv[e1], g2 = sv[e2], g3 = sv[e3];
      ACC2(v0, g0) ACC2(v1, g1) ACC2(v2, g2) ACC2(v3, g3)
    }
    for (int e = nf + q; e < d; e += 4) {
      uint2 v = rowp[(size_t)sk[e] * 64 + r];
      float g = sv[e];
      ACC2(v, g)
    }
    __syncthreads();
  }
#undef ACC2

  if (q != 0) {
#pragma unroll
    for (int j = 0; j < 8; ++j) cmb[q - 1][r][j] = a[j];
  }
  __syncthreads();
  if (q == 0) {
#pragma unroll
    for (int w = 0; w < 3; ++w)
#pragma unroll
      for (int j = 0; j < 8; ++j) a[j] += cmb[w][r][j];
    const float SC = 1.0507009873554805f, AL = 1.6732632423543772f;
    float p[NK];
#pragma unroll
    for (int k = 0; k < NK; ++k) p[k] = 0.f;
#pragma unroll
    for (int j = 0; j < 8; ++j) {
      int dim = r * 8 + j;
      float v = a[j] + bias[dim];
      v = (v > 0.f) ? SC * v : SC * AL * (expf(v) - 1.f);
      const float* wrow = Wt + (size_t)dim * NK;
#pragma unroll
      for (int k = 0; k < NK; ++k) p[k] = fmaf(v, wrow[k], p[k]);
    }
#pragma unroll
    for (int off = 32; off >= 1; off >>= 1)
#pragma unroll
      for (int k = 0; k < NK; ++k) p[k] += __shfl_down(p[k], off, 64);
    if (r == 0) {
#pragma unroll
      for (int k = 0; k < NK; ++k) red[k] = p[k];
    }
  }
  __syncthreads();
  if (t < NK) {
    float l = red[t] + bt[t];
    float m = l;
#pragma unroll
    for (int off = 8; off >= 1; off >>= 1) m = fmaxf(m, __shfl_xor(m, off, 16));
    float ex = expf(l - m);
    float s = ex;
#pragma unroll
    for (int off = 8; off >= 1; off >>= 1) s += __shfl_xor(s, off, 16);
    assign[(size_t)node * NK + t] = ex / s;
  }
}

// ---------------- cs/nl block partials (NO atomics) ----------------
__global__ __launch_bounds__(256) void reduce_cs_nl(const float* __restrict__ assign,
                                                    const float* __restrict__ deg,
                                                    float* __restrict__ P1, int n) {
  __shared__ float lds[4][32];
  float cs[NK] = {}, nl[NK] = {};
  for (int i = blockIdx.x * blockDim.x + threadIdx.x; i < n; i += gridDim.x * blockDim.x) {
    float d = deg[i];
    const float4* ap = (const float4*)(assign + (size_t)i * NK);
#pragma unroll
    for (int q = 0; q < 4; ++q) {
      float4 a = ap[q];
      cs[q * 4 + 0] += a.x; cs[q * 4 + 1] += a.y;
      cs[q * 4 + 2] += a.z; cs[q * 4 + 3] += a.w;
      nl[q * 4 + 0] = fmaf(a.x, d, nl[q * 4 + 0]);
      nl[q * 4 + 1] = fmaf(a.y, d, nl[q * 4 + 1]);
      nl[q * 4 + 2] = fmaf(a.z, d, nl[q * 4 + 2]);
      nl[q * 4 + 3] = fmaf(a.w, d, nl[q * 4 + 3]);
    }
  }
#pragma unroll
  for (int off = 32; off >= 1; off >>= 1) {
#pragma unroll
    for (int k = 0; k < NK; ++k) {
      cs[k] += __shfl_down(cs[k], off, 64);
      nl[k] += __shfl_down(nl[k], off, 64);
    }
  }
  int wave = threadIdx.x >> 6, lane = threadIdx.x & 63;
  if (lane == 0) {
#pragma unroll
    for (int k = 0; k < NK; ++k) { lds[wave][k] = cs[k]; lds[wave][NK + k] = nl[k]; }
  }
  __syncthreads();
  if (threadIdx.x < 32)
    P1[(size_t)blockIdx.x * 32 + threadIdx.x] =
        lds[0][threadIdx.x] + lds[1][threadIdx.x] + lds[2][threadIdx.x] + lds[3][threadIdx.x];
}

// ---------------- trace block partials (NO atomics) ----------------
__global__ __launch_bounds__(256) void trace_kernel(const int* __restrict__ src,
                                                    const int* __restrict__ dst,
                                                    const float* __restrict__ gv,
                                                    const float* __restrict__ assign,
                                                    float* __restrict__ T2, int E) {
  __shared__ float lds[4];
  float t = 0.f;
  for (int e = blockIdx.x * blockDim.x + threadIdx.x; e < E; e += gridDim.x * blockDim.x) {
    int s = src[e], d = dst[e];
    const float4* as = (const float4*)(assign + (size_t)s * NK);
    const float4* ad = (const float4*)(assign + (size_t)d * NK);
    float dot = 0.f;
#pragma unroll
    for (int q = 0; q < 4; ++q) {
      float4 x = as[q], y = ad[q];
      dot += x.x * y.x + x.y * y.y + x.z * y.z + x.w * y.w;
    }
    t = fmaf(gv[e], dot, t);
  }
#pragma unroll
  for (int off = 32; off >= 1; off >>= 1) t += __shfl_down(t, off, 64);
  int wave = threadIdx.x >> 6, lane = threadIdx.x & 63;
  if (lane == 0) lds[wave] = t;
  __syncthreads();
  if (threadIdx.x == 0) T2[blockIdx.x] = lds[0] + lds[1] + lds[2] + lds[3];
}

// ---------------- final: sum partials -> scalar ----------------
__global__ __launch_bounds__(256) void final_kernel(const float* __restrict__ P1,
                                                    const float* __restrict__ T2,
                                                    float* __restrict__ out,
                                                    int np1, int np2, int E, int n) {
  __shared__ float arr[256];
  __shared__ float csnl[32];
  const int t = threadIdx.x;
  float s = 0.f;
  for (int p = (t >> 5); p < np1; p += 8) s += P1[(size_t)p * 32 + (t & 31)];
  arr[t] = s;
  __syncthreads();
  if (t < 32) {
    float v = 0.f;
#pragma unroll
    for (int j = 0; j < 8; ++j) v += arr[t + j * 32];
    csnl[t] = v;
  }
  __syncthreads();
  float tv = 0.f;
  for (int p = t; p < np2; p += 256) tv += T2[p];
  arr[t] = tv;
  __syncthreads();
  if (t == 0) {
    float tp = 0.f;
    for (int j = 0; j < 256; ++j) tp += arr[j];
    float sc = 0.f, sn = 0.f;
#pragma unroll
    for (int k = 0; k < NK; ++k) {
      sc += csnl[k] * csnl[k];
      sn += csnl[NK + k] * csnl[NK + k];
    }
    float twoE = 2.0f * (float)E;
    float spectral = -(tp - sn / twoE) / twoE;
    float closs = (sqrtf(sc) / (float)n) * 4.0f - 1.0f;
    out[0] = spectral + closs;
  }
}

extern "C" void kernel_launch(void* const* d_in, const int* in_sizes, int n_in,
                              void* d_out, int out_size, void* d_ws, size_t ws_size,
                              hipStream_t stream) {
  const int*   src  = (const int*)d_in[0];
  const int*   dst  = (const int*)d_in[1];
  const float* gv   = (const float*)d_in[2];
  const float* gn   = (const float*)d_in[3];
  const float* feat = (const float*)d_in[4];
  const float* W    = (const float*)d_in[5];
  const float* b    = (const float*)d_in[6];
  const float* Wt   = (const float*)d_in[7];
  const float* bt   = (const float*)d_in[8];
  const int E = in_sizes[0];
  const int N = in_sizes[4] / NF;
  const int Mblocks = (N + GBM - 1) / GBM;
  const int Mpad = Mblocks * GBM;
  const int nsb = (N + 1023) / 1024;   // scan blocks (49 for N=50000, <= 64)

  char* ws = (char*)d_ws;
  size_t off = 0;
  auto alloc = [&](size_t bytes) {
    void* p = ws + off;
    off += (bytes + 255) & ~(size_t)255;
    return p;
  };
  unsigned short* feat_bf = (unsigned short*)alloc((size_t)N * NF * sizeof(unsigned short));
  unsigned short* Wp      = (unsigned short*)alloc((size_t)NF * NH * sizeof(unsigned short));
  unsigned char*  xw8     = (unsigned char*)alloc((size_t)Mpad * NH);
  int*   counts = (int*)alloc((size_t)N * sizeof(int));
  int*   offs   = (int*)alloc((size_t)(N + 1) * sizeof(int));
  int*   cursor = (int*)alloc((size_t)N * sizeof(int));
  float* deg    = (float*)alloc((size_t)N * sizeof(float));
  int2*  epair  = (int2*)alloc((size_t)E * sizeof(int2));
  float* assign = (float*)alloc((size_t)N * NK * sizeof(float));
  float* P1     = (float*)alloc((size_t)RPART * 32 * sizeof(float));
  float* T2     = (float*)alloc((size_t)TPART * sizeof(float));
  int*   bsum   = (int*)alloc(64 * sizeof(int));
  int*   bbase  = (int*)alloc(64 * sizeof(int));
  (void)ws_size; (void)n_in; (void)out_size;

  hipMemsetAsync(counts, 0, (size_t)N * sizeof(int), stream);
  hipMemsetAsync(deg, 0, (size_t)N * sizeof(float), stream);

  conv_feat<<<2048, 256, 0, stream>>>(feat, feat_bf, N * NF / 4);
  conv_w<<<(NF * NH) / 256, 256, 0, stream>>>(W, Wp);

  dim3 ggrid(NH / GBN, Mblocks);
  gemm_bf16<<<ggrid, 256, 0, stream>>>(feat_bf, Wp, xw8, N);

  int eblocks = (E + 255) / 256;
  hist_kernel<<<eblocks, 256, 0, stream>>>(src, dst, gv, counts, deg, E);
  scanA<<<nsb, 256, 0, stream>>>(counts, bsum, N);
  scanB<<<1, 64, 0, stream>>>(bsum, bbase, offs, nsb, N);
  scanC<<<nsb, 256, 0, stream>>>(counts, bbase, offs, cursor, N);
  scatter_kernel<<<eblocks, 256, 0, stream>>>(src, dst, gn, cursor, epair, E);

  node_kernel<<<N, 256, 0, stream>>>((const unsigned*)xw8, offs, epair, b, Wt, bt, assign, N);

  reduce_cs_nl<<<RPART, 256, 0, stream>>>(assign, deg, P1, N);
  trace_kernel<<<TPART, 256, 0, stream>>>(src, dst, gv, assign, T2, E);
  final_kernel<<<1, 256, 0, stream>>>(P1, T2, (float*)d_out, RPART, TPART, E, N);
}

// Round 18
// 660.754 us; speedup vs baseline: 1.2889x; 1.2889x over previous
//
#include <hip/hip_runtime.h>
#include <math.h>

#define NN 50000
#define NF 512
#define NH 512
#define NK 16

typedef __attribute__((ext_vector_type(8))) short bf16x8;
typedef __attribute__((ext_vector_type(4))) float f32x4;
typedef __attribute__((ext_vector_type(2))) float f32x2;

#define RPART 128   // reduce_cs_nl blocks
#define TPART 2048  // trace blocks

__device__ __forceinline__ unsigned short f2bf(float f) {
  unsigned u = __float_as_uint(f);
  unsigned r = (u + 0x7fffu + ((u >> 16) & 1u)) >> 16;
  return (unsigned short)r;
}

// ---------------- fused fp32->bf16 conversion: feat (n4 float4s) + W packing ----------------
__global__ __launch_bounds__(256) void conv_all(const float* __restrict__ X,
                                                unsigned short* __restrict__ Xb, int n4,
                                                const float* __restrict__ W,
                                                unsigned short* __restrict__ Bp) {
  int gid = blockIdx.x * blockDim.x + threadIdx.x;
  // job 1: feature conversion (grid-stride over n4 float4 chunks)
  for (int i = gid; i < n4; i += gridDim.x * blockDim.x) {
    float4 v = *(const float4*)(X + (size_t)i * 4);
    ushort4 o;
    o.x = f2bf(v.x); o.y = f2bf(v.y); o.z = f2bf(v.z); o.w = f2bf(v.w);
    *(ushort4*)(Xb + (size_t)i * 4) = o;
  }
  // job 2: W -> packed bf16: Bp[((k>>3)*512 + col)*8 + (k&7)]
  for (int idx = gid; idx < NF * NH; idx += gridDim.x * blockDim.x) {
    int k = idx >> 9, col = idx & 511;
    Bp[((size_t)(k >> 3) * 512 + col) * 8 + (k & 7)] = f2bf(W[idx]);
  }
}

// ---------------- GEMM: xw_fp8[Mpad,512] = feat_bf @ W (bf16 MFMA, fp8 out, row-major) ----------------
#define GBM 128
#define GBN 128
#define GBK 32

__global__ __launch_bounds__(256) void gemm_bf16(const unsigned short* __restrict__ A,
                                                 const unsigned short* __restrict__ Bp,
                                                 unsigned char* __restrict__ C8, int M) {
  __shared__ bf16x8 Abuf[512];
  __shared__ bf16x8 Bbuf[512];
  const int tid = threadIdx.x;
  const int lane = tid & 63;
  const int w = tid >> 6;
  const int wr = w >> 1, wc = w & 1;
  const int bm0 = blockIdx.y * GBM;
  const int bn0 = blockIdx.x * GBN;

  f32x4 acc[4][4];
#pragma unroll
  for (int m = 0; m < 4; ++m)
#pragma unroll
    for (int n = 0; n < 4; ++n)
      acc[m][n] = (f32x4){0.f, 0.f, 0.f, 0.f};

  for (int k0 = 0; k0 < NF; k0 += GBK) {
#pragma unroll
    for (int c = 0; c < 2; ++c) {
      int slot = c * 256 + tid;
      int kc = slot >> 7;
      int rc = slot & 127;
      int gr = bm0 + rc; if (gr > M - 1) gr = M - 1;
      Abuf[slot] = *(const bf16x8*)(A + (size_t)gr * NF + k0 + kc * 8);
      int kcg = (k0 >> 3) + kc;
      Bbuf[slot] = *(const bf16x8*)(Bp + ((size_t)kcg * NH + bn0 + rc) * 8);
    }
    __syncthreads();
    bf16x8 af[4], bfr[4];
#pragma unroll
    for (int m = 0; m < 4; ++m)
      af[m] = Abuf[(lane >> 4) * 128 + wr * 64 + m * 16 + (lane & 15)];
#pragma unroll
    for (int n = 0; n < 4; ++n)
      bfr[n] = Bbuf[(lane >> 4) * 128 + wc * 64 + n * 16 + (lane & 15)];
#pragma unroll
    for (int m = 0; m < 4; ++m)
#pragma unroll
      for (int n = 0; n < 4; ++n)
        acc[m][n] = __builtin_amdgcn_mfma_f32_16x16x32_bf16(af[m], bfr[n], acc[m][n], 0, 0, 0);
    __syncthreads();
  }
#pragma unroll
  for (int m = 0; m < 4; ++m) {
    int grow_base = bm0 + wr * 64 + m * 16 + (lane >> 4) * 4;
#pragma unroll
    for (int r = 0; r < 4; ++r) {
      int grow = grow_base + r;
#pragma unroll
      for (int n = 0; n < 4; ++n) {
        int gcol = bn0 + wc * 64 + n * 16 + (lane & 15);
        int pk = __builtin_amdgcn_cvt_pk_fp8_f32(acc[m][n][r], 0.f, 0, false);
        C8[(size_t)grow * NH + gcol] = (unsigned char)(pk & 0xFF);
      }
    }
  }
}

// ---------------- edge histogram + degrees ----------------
__global__ void hist_kernel(const int* __restrict__ src, const int* __restrict__ dst,
                            const float* __restrict__ gv, int* __restrict__ counts,
                            float* __restrict__ deg, int E) {
  int e = blockIdx.x * blockDim.x + threadIdx.x;
  if (e < E) {
    atomicAdd(&counts[src[e]], 1);
    atomicAdd(&deg[dst[e]], gv[e]);
  }
}

// ---------------- parallel 3-phase exclusive scan ----------------
__global__ __launch_bounds__(256) void scanA(const int* __restrict__ counts,
                                             int* __restrict__ bsum, int n) {
  __shared__ int ws[4];
  int i0 = blockIdx.x * 1024 + threadIdx.x * 4;
  int s = 0;
  if (i0 + 3 < n) {
    int4 v = *(const int4*)(counts + i0);
    s = v.x + v.y + v.z + v.w;
  } else {
#pragma unroll
    for (int j = 0; j < 4; ++j) if (i0 + j < n) s += counts[i0 + j];
  }
#pragma unroll
  for (int off = 32; off >= 1; off >>= 1) s += __shfl_down(s, off, 64);
  int wv = threadIdx.x >> 6, ln = threadIdx.x & 63;
  if (ln == 0) ws[wv] = s;
  __syncthreads();
  if (threadIdx.x == 0) bsum[blockIdx.x] = ws[0] + ws[1] + ws[2] + ws[3];
}

__global__ __launch_bounds__(64) void scanB(const int* __restrict__ bsum,
                                            int* __restrict__ bbase,
                                            int* __restrict__ offs, int nb, int n) {
  int ln = threadIdx.x;
  int v = ln < nb ? bsum[ln] : 0;
  int x = v;
#pragma unroll
  for (int d = 1; d < 64; d <<= 1) {
    int y = __shfl_up(x, d, 64);
    if (ln >= d) x += y;
  }
  if (ln < nb) bbase[ln] = x - v;
  if (ln == nb - 1) offs[n] = x;
}

__global__ __launch_bounds__(256) void scanC(const int* __restrict__ counts,
                                             const int* __restrict__ bbase,
                                             int* __restrict__ offs,
                                             int* __restrict__ cursor, int n) {
  __shared__ int ws[4];
  int i0 = blockIdx.x * 1024 + threadIdx.x * 4;
  int c0 = 0, c1 = 0, c2 = 0, c3 = 0;
  if (i0 + 3 < n) {
    int4 v = *(const int4*)(counts + i0);
    c0 = v.x; c1 = v.y; c2 = v.z; c3 = v.w;
  } else {
    if (i0 < n)     c0 = counts[i0];
    if (i0 + 1 < n) c1 = counts[i0 + 1];
    if (i0 + 2 < n) c2 = counts[i0 + 2];
    if (i0 + 3 < n) c3 = counts[i0 + 3];
  }
  int s = c0 + c1 + c2 + c3;
  int x = s;
  int wv = threadIdx.x >> 6, ln = threadIdx.x & 63;
#pragma unroll
  for (int d = 1; d < 64; d <<= 1) {
    int y = __shfl_up(x, d, 64);
    if (ln >= d) x += y;
  }
  if (ln == 63) ws[wv] = x;
  __syncthreads();
  int woff = 0;
  if (wv > 0) woff += ws[0];
  if (wv > 1) woff += ws[1];
  if (wv > 2) woff += ws[2];
  int exc = bbase[blockIdx.x] + woff + x - s;
  if (i0 < n)     { offs[i0]     = exc;                cursor[i0]     = exc; }
  if (i0 + 1 < n) { offs[i0 + 1] = exc + c0;           cursor[i0 + 1] = exc + c0; }
  if (i0 + 2 < n) { offs[i0 + 2] = exc + c0 + c1;      cursor[i0 + 2] = exc + c0 + c1; }
  if (i0 + 3 < n) { offs[i0 + 3] = exc + c0 + c1 + c2; cursor[i0 + 3] = exc + c0 + c1 + c2; }
}

// ---------------- scatter edges into CSR (paired 8B stores) ----------------
__global__ void scatter_kernel(const int* __restrict__ src, const int* __restrict__ dst,
                               const float* __restrict__ gn, int* __restrict__ cursor,
                               int2* __restrict__ epair, int E) {
  int e = blockIdx.x * blockDim.x + threadIdx.x;
  if (e < E) {
    int pos = atomicAdd(&cursor[src[e]], 1);
    int2 v; v.x = dst[e]; v.y = __float_as_int(gn[e]);
    epair[pos] = v;
  }
}

// ---------------- fused per-node: fp8 SpMM + selu + proj + softmax (R15 proven config) ----------------
__global__ __launch_bounds__(256) void node_kernel(const unsigned* __restrict__ xw8,
                                                   const int* __restrict__ offs,
                                                   const int2* __restrict__ epair,
                                                   const float* __restrict__ bias,
                                                   const float* __restrict__ Wt,
                                                   const float* __restrict__ bt,
                                                   float* __restrict__ assign, int n) {
  __shared__ int sk[256];
  __shared__ float sv[256];
  __shared__ float cmb[128][4];
  __shared__ float red[2][NK];
  int node = blockIdx.x;
  if (node >= n) return;
  const int t = threadIdx.x;
  const int hl = t & 127;
  const int q = t >> 7;
  const int beg = offs[node], end = offs[node + 1];

  float a0 = 0.f, a1 = 0.f, a2 = 0.f, a3 = 0.f;

  for (int cbeg = beg; cbeg < end; cbeg += 256) {
    int d = end - cbeg; if (d > 256) d = 256;
    if (t < d) { int2 p = epair[cbeg + t]; sk[t] = p.x; sv[t] = __int_as_float(p.y); }
    __syncthreads();
#define ACC(V, G)                                                     \
    { f32x2 lo = __builtin_amdgcn_cvt_pk_f32_fp8(V, false);           \
      f32x2 hi = __builtin_amdgcn_cvt_pk_f32_fp8(V, true);            \
      a0 = fmaf(G, lo[0], a0); a1 = fmaf(G, lo[1], a1);               \
      a2 = fmaf(G, hi[0], a2); a3 = fmaf(G, hi[1], a3); }
    int nf = d & ~7;
    for (int b = 0; b < nf; b += 8) {
      int e0 = b + q, e1 = b + 2 + q, e2 = b + 4 + q, e3 = b + 6 + q;
      int i0 = sk[e0], i1 = sk[e1], i2 = sk[e2], i3 = sk[e3];
      unsigned v0 = xw8[(size_t)i0 * 128 + hl];
      unsigned v1 = xw8[(size_t)i1 * 128 + hl];
      unsigned v2 = xw8[(size_t)i2 * 128 + hl];
      unsigned v3 = xw8[(size_t)i3 * 128 + hl];
      float g0 = sv[e0], g1 = sv[e1], g2 = sv[e2], g3 = sv[e3];
      ACC(v0, g0) ACC(v1, g1) ACC(v2, g2) ACC(v3, g3)
    }
    for (int e = nf + q; e < d; e += 2) {
      unsigned v = xw8[(size_t)sk[e] * 128 + hl];
      float g = sv[e];
      ACC(v, g)
    }
#undef ACC
    __syncthreads();
  }

  if (q == 1) { cmb[hl][0] = a0; cmb[hl][1] = a1; cmb[hl][2] = a2; cmb[hl][3] = a3; }
  __syncthreads();
  if (q == 0) {
    a0 += cmb[hl][0]; a1 += cmb[hl][1]; a2 += cmb[hl][2]; a3 += cmb[hl][3];
    float a[4] = {a0, a1, a2, a3};
    const float SC = 1.0507009873554805f, AL = 1.6732632423543772f;
    float p[NK];
#pragma unroll
    for (int k = 0; k < NK; ++k) p[k] = 0.f;
#pragma unroll
    for (int j = 0; j < 4; ++j) {
      int dim = hl * 4 + j;
      float v = a[j] + bias[dim];
      v = (v > 0.f) ? SC * v : SC * AL * (expf(v) - 1.f);
      const float* wrow = Wt + (size_t)dim * NK;
#pragma unroll
      for (int k = 0; k < NK; ++k) p[k] = fmaf(v, wrow[k], p[k]);
    }
#pragma unroll
    for (int off = 32; off >= 1; off >>= 1)
#pragma unroll
      for (int k = 0; k < NK; ++k) p[k] += __shfl_down(p[k], off, 64);
    int wave = t >> 6, lane = t & 63;
    if (lane == 0) {
#pragma unroll
      for (int k = 0; k < NK; ++k) red[wave][k] = p[k];
    }
  }
  __syncthreads();
  if (t < NK) {
    float l = red[0][t] + red[1][t] + bt[t];
    float m = l;
#pragma unroll
    for (int off = 8; off >= 1; off >>= 1) m = fmaxf(m, __shfl_xor(m, off, 16));
    float ex = expf(l - m);
    float s = ex;
#pragma unroll
    for (int off = 8; off >= 1; off >>= 1) s += __shfl_xor(s, off, 16);
    assign[(size_t)node * NK + t] = ex / s;
  }
}

// ---------------- cs/nl block partials (NO atomics) ----------------
__global__ __launch_bounds__(256) void reduce_cs_nl(const float* __restrict__ assign,
                                                    const float* __restrict__ deg,
                                                    float* __restrict__ P1, int n) {
  __shared__ float lds[4][32];
  float cs[NK] = {}, nl[NK] = {};
  for (int i = blockIdx.x * blockDim.x + threadIdx.x; i < n; i += gridDim.x * blockDim.x) {
    float d = deg[i];
    const float4* ap = (const float4*)(assign + (size_t)i * NK);
#pragma unroll
    for (int q = 0; q < 4; ++q) {
      float4 a = ap[q];
      cs[q * 4 + 0] += a.x; cs[q * 4 + 1] += a.y;
      cs[q * 4 + 2] += a.z; cs[q * 4 + 3] += a.w;
      nl[q * 4 + 0] = fmaf(a.x, d, nl[q * 4 + 0]);
      nl[q * 4 + 1] = fmaf(a.y, d, nl[q * 4 + 1]);
      nl[q * 4 + 2] = fmaf(a.z, d, nl[q * 4 + 2]);
      nl[q * 4 + 3] = fmaf(a.w, d, nl[q * 4 + 3]);
    }
  }
#pragma unroll
  for (int off = 32; off >= 1; off >>= 1) {
#pragma unroll
    for (int k = 0; k < NK; ++k) {
      cs[k] += __shfl_down(cs[k], off, 64);
      nl[k] += __shfl_down(nl[k], off, 64);
    }
  }
  int wave = threadIdx.x >> 6, lane = threadIdx.x & 63;
  if (lane == 0) {
#pragma unroll
    for (int k = 0; k < NK; ++k) { lds[wave][k] = cs[k]; lds[wave][NK + k] = nl[k]; }
  }
  __syncthreads();
  if (threadIdx.x < 32)
    P1[(size_t)blockIdx.x * 32 + threadIdx.x] =
        lds[0][threadIdx.x] + lds[1][threadIdx.x] + lds[2][threadIdx.x] + lds[3][threadIdx.x];
}

// ---------------- trace block partials (NO atomics) ----------------
__global__ __launch_bounds__(256) void trace_kernel(const int* __restrict__ src,
                                                    const int* __restrict__ dst,
                                                    const float* __restrict__ gv,
                                                    const float* __restrict__ assign,
                                                    float* __restrict__ T2, int E) {
  __shared__ float lds[4];
  float t = 0.f;
  for (int e = blockIdx.x * blockDim.x + threadIdx.x; e < E; e += gridDim.x * blockDim.x) {
    int s = src[e], d = dst[e];
    const float4* as = (const float4*)(assign + (size_t)s * NK);
    const float4* ad = (const float4*)(assign + (size_t)d * NK);
    float dot = 0.f;
#pragma unroll
    for (int q = 0; q < 4; ++q) {
      float4 x = as[q], y = ad[q];
      dot += x.x * y.x + x.y * y.y + x.z * y.z + x.w * y.w;
    }
    t = fmaf(gv[e], dot, t);
  }
#pragma unroll
  for (int off = 32; off >= 1; off >>= 1) t += __shfl_down(t, off, 64);
  int wave = threadIdx.x >> 6, lane = threadIdx.x & 63;
  if (lane == 0) lds[wave] = t;
  __syncthreads();
  if (threadIdx.x == 0) T2[blockIdx.x] = lds[0] + lds[1] + lds[2] + lds[3];
}

// ---------------- final: sum partials -> scalar ----------------
__global__ __launch_bounds__(256) void final_kernel(const float* __restrict__ P1,
                                                    const float* __restrict__ T2,
                                                    float* __restrict__ out,
                                                    int np1, int np2, int E, int n) {
  __shared__ float arr[256];
  __shared__ float csnl[32];
  const int t = threadIdx.x;
  float s = 0.f;
  for (int p = (t >> 5); p < np1; p += 8) s += P1[(size_t)p * 32 + (t & 31)];
  arr[t] = s;
  __syncthreads();
  if (t < 32) {
    float v = 0.f;
#pragma unroll
    for (int j = 0; j < 8; ++j) v += arr[t + j * 32];
    csnl[t] = v;
  }
  __syncthreads();
  float tv = 0.f;
  for (int p = t; p < np2; p += 256) tv += T2[p];
  arr[t] = tv;
  __syncthreads();
  if (t == 0) {
    float tp = 0.f;
    for (int j = 0; j < 256; ++j) tp += arr[j];
    float sc = 0.f, sn = 0.f;
#pragma unroll
    for (int k = 0; k < NK; ++k) {
      sc += csnl[k] * csnl[k];
      sn += csnl[NK + k] * csnl[NK + k];
    }
    float twoE = 2.0f * (float)E;
    float spectral = -(tp - sn / twoE) / twoE;
    float closs = (sqrtf(sc) / (float)n) * 4.0f - 1.0f;
    out[0] = spectral + closs;
  }
}

extern "C" void kernel_launch(void* const* d_in, const int* in_sizes, int n_in,
                              void* d_out, int out_size, void* d_ws, size_t ws_size,
                              hipStream_t stream) {
  const int*   src  = (const int*)d_in[0];
  const int*   dst  = (const int*)d_in[1];
  const float* gv   = (const float*)d_in[2];
  const float* gn   = (const float*)d_in[3];
  const float* feat = (const float*)d_in[4];
  const float* W    = (const float*)d_in[5];
  const float* b    = (const float*)d_in[6];
  const float* Wt   = (const float*)d_in[7];
  const float* bt   = (const float*)d_in[8];
  const int E = in_sizes[0];
  const int N = in_sizes[4] / NF;
  const int Mblocks = (N + GBM - 1) / GBM;
  const int Mpad = Mblocks * GBM;
  const int nsb = (N + 1023) / 1024;   // scan blocks (49 for N=50000, <= 64)

  char* ws = (char*)d_ws;
  size_t off = 0;
  auto alloc = [&](size_t bytes) {
    void* p = ws + off;
    off += (bytes + 255) & ~(size_t)255;
    return p;
  };
  unsigned short* feat_bf = (unsigned short*)alloc((size_t)N * NF * sizeof(unsigned short));
  unsigned short* Wp      = (unsigned short*)alloc((size_t)NF * NH * sizeof(unsigned short));
  unsigned char*  xw8     = (unsigned char*)alloc((size_t)Mpad * NH);
  int*   counts = (int*)alloc((size_t)N * sizeof(int));       // counts+deg adjacent:
  float* deg    = (float*)alloc((size_t)N * sizeof(float));   // one memset covers both
  int*   offs   = (int*)alloc((size_t)(N + 1) * sizeof(int));
  int*   cursor = (int*)alloc((size_t)N * sizeof(int));
  int2*  epair  = (int2*)alloc((size_t)E * sizeof(int2));
  float* assign = (float*)alloc((size_t)N * NK * sizeof(float));
  float* P1     = (float*)alloc((size_t)RPART * 32 * sizeof(float));
  float* T2     = (float*)alloc((size_t)TPART * sizeof(float));
  int*   bsum   = (int*)alloc(64 * sizeof(int));
  int*   bbase  = (int*)alloc(64 * sizeof(int));
  (void)ws_size; (void)n_in; (void)out_size;

  // counts and deg are adjacent (256B-aligned gap is inside the rounded region)
  hipMemsetAsync(counts, 0, (char*)(deg + N) - (char*)counts, stream);

  conv_all<<<2048, 256, 0, stream>>>(feat, feat_bf, N * NF / 4, W, Wp);

  dim3 ggrid(NH / GBN, Mblocks);
  gemm_bf16<<<ggrid, 256, 0, stream>>>(feat_bf, Wp, xw8, N);

  int eblocks = (E + 255) / 256;
  hist_kernel<<<eblocks, 256, 0, stream>>>(src, dst, gv, counts, deg, E);
  scanA<<<nsb, 256, 0, stream>>>(counts, bsum, N);
  scanB<<<1, 64, 0, stream>>>(bsum, bbase, offs, nsb, N);
  scanC<<<nsb, 256, 0, stream>>>(counts, bbase, offs, cursor, N);
  scatter_kernel<<<eblocks, 256, 0, stream>>>(src, dst, gn, cursor, epair, E);

  node_kernel<<<N, 256, 0, stream>>>((const unsigned*)xw8, offs, epair, b, Wt, bt, assign, N);

  reduce_cs_nl<<<RPART, 256, 0, stream>>>(assign, deg, P1, N);
  trace_kernel<<<TPART, 256, 0, stream>>>(src, dst, gv, assign, T2, E);
  final_kernel<<<1, 256, 0, stream>>>(P1, T2, (float*)d_out, RPART, TPART, E, N);
}